// Round 2
// 458.890 us; speedup vs baseline: 1.0406x; 1.0406x over previous
//
#include <hip/hip_runtime.h>

// S4D (buggy-faithful reference): the whole FFT pipeline reduces to
//   y[b,t,d] = (k0[d] + D[d]) * u[b,t,d] + k1[d] * u[b,t-1,d]
// where [k0,k1] is the length-h (=2) "kernel" from the reference:
//   dA = [[z0,-1],[-1,z1]] (off-diag are -1 by the elementwise division),
//   P  = dA^L (L=256 -> 8 squarings), M = I - P,
//   k_n = Re( C_n * (M[n,0]*B0 + M[n,1]*B1) ).
// Entries of P reach ~2e19, so the setup math is done in fp64.

#define D_MODEL 2048
#define BATCH   128
#define LSEQ    256
#define HSTATE  2
#define T_CHUNK 32   // 32 -> grid 2048 blocks = 8 blocks/CU = occupancy cap

// Native clang vector type: __builtin_nontemporal_store requires a scalar or
// native vector (HIP's float4 is a class and is rejected).
typedef float v4f __attribute__((ext_vector_type(4)));

struct cd { double re, im; };
__device__ __forceinline__ cd cmul(cd a, cd b) {
    return { a.re*b.re - a.im*b.im, a.re*b.im + a.im*b.re };
}
__device__ __forceinline__ cd cadd(cd a, cd b) { return { a.re + b.re, a.im + b.im }; }
__device__ __forceinline__ cd cdiv(cd a, cd b) {
    double inv = 1.0 / (b.re*b.re + b.im*b.im);
    return { (a.re*b.re + a.im*b.im) * inv, (a.im*b.re - a.re*b.im) * inv };
}

// One thread per channel d: compute c0[d] = k0[d] + D[d], c1[d] = k1[d].
__global__ __launch_bounds__(256) void s4d_coef_kernel(
        const float* __restrict__ A_real, const float* __restrict__ A_imag,
        const float* __restrict__ B_real, const float* __restrict__ B_imag,
        const float* __restrict__ C_real, const float* __restrict__ C_imag,
        const float* __restrict__ Dp,
        float* __restrict__ c0, float* __restrict__ c1) {
    int d = blockIdx.x * blockDim.x + threadIdx.x;
    if (d >= D_MODEL) return;

    // z_n = (1 + A_n/2) / (1 - A_n/2),  A_n = -exp(A_real) + i*A_imag
    cd z[HSTATE];
    #pragma unroll
    for (int n = 0; n < HSTATE; ++n) {
        double ar = -exp((double)A_real[d * HSTATE + n]);
        double ai = (double)A_imag[d * HSTATE + n];
        cd num = { 1.0 + 0.5 * ar,  0.5 * ai };
        cd den = { 1.0 - 0.5 * ar, -0.5 * ai };
        z[n] = cdiv(num, den);
    }

    // dA = [[z0, -1], [-1, z1]];  P = dA^256 via 8 squarings (fp64)
    cd m00 = z[0], m01 = { -1.0, 0.0 }, m10 = { -1.0, 0.0 }, m11 = z[1];
    #pragma unroll
    for (int s = 0; s < 8; ++s) {
        cd a = cadd(cmul(m00, m00), cmul(m01, m10));
        cd b = cadd(cmul(m00, m01), cmul(m01, m11));
        cd c = cadd(cmul(m10, m00), cmul(m11, m10));
        cd e = cadd(cmul(m10, m01), cmul(m11, m11));
        m00 = a; m01 = b; m10 = c; m11 = e;
    }

    // M = I - P
    cd M00 = { 1.0 - m00.re, -m00.im }, M01 = { -m01.re, -m01.im };
    cd M10 = { -m10.re, -m10.im },      M11 = { 1.0 - m11.re, -m11.im };

    cd B0 = { (double)B_real[d*2+0], (double)B_imag[d*2+0] };
    cd B1 = { (double)B_real[d*2+1], (double)B_imag[d*2+1] };
    cd C0 = { (double)C_real[d*2+0], (double)C_imag[d*2+0] };
    cd C1 = { (double)C_real[d*2+1], (double)C_imag[d*2+1] };

    cd k0 = cmul(C0, cadd(cmul(M00, B0), cmul(M01, B1)));
    cd k1 = cmul(C1, cadd(cmul(M10, B0), cmul(M11, B1)));

    c0[d] = (float)(k0.re + (double)Dp[d]);
    c1[d] = (float)k1.re;
}

// 2-tap causal conv along t, channels innermost (coalesced 16B loads).
// grid = (D_MODEL/1024, LSEQ/T_CHUNK, BATCH); block = 256 threads;
// each thread owns 4 consecutive channels and marches T_CHUNK steps in t,
// keeping u[t-1] in register -> every u element loaded exactly once
// (plus one boundary row per t-chunk, +3% at T_CHUNK=32).
// T_CHUNK=32: 2048 blocks -> 8 blocks/CU (the HW cap at 24 VGPR);
// unroll 8 keeps 8 independent 1 KiB loads in flight per wave;
// non-temporal stores keep the write-once output out of L3 so u (256 MB,
// = L3 size) stays resident across bench iterations.
__global__ __launch_bounds__(256) void s4d_conv_kernel(
        const float* __restrict__ u,
        const float* __restrict__ c0, const float* __restrict__ c1,
        float* __restrict__ out) {
    const int d  = blockIdx.x * 1024 + threadIdx.x * 4;
    const int b  = blockIdx.z;
    const int t0 = blockIdx.y * T_CHUNK;

    const v4f k0 = *reinterpret_cast<const v4f*>(c0 + d);
    const v4f k1 = *reinterpret_cast<const v4f*>(c1 + d);

    const size_t base = (size_t)b * LSEQ * D_MODEL + (size_t)d;

    v4f prev;
    if (t0 == 0) {
        prev = (v4f){0.f, 0.f, 0.f, 0.f};
    } else {
        prev = *reinterpret_cast<const v4f*>(u + base + (size_t)(t0 - 1) * D_MODEL);
    }

    #pragma unroll 8
    for (int t = t0; t < t0 + T_CHUNK; ++t) {
        const size_t off = base + (size_t)t * D_MODEL;
        v4f cur = *reinterpret_cast<const v4f*>(u + off);
        v4f y;
        y.x = fmaf(k1.x, prev.x, k0.x * cur.x);
        y.y = fmaf(k1.y, prev.y, k0.y * cur.y);
        y.z = fmaf(k1.z, prev.z, k0.z * cur.z);
        y.w = fmaf(k1.w, prev.w, k0.w * cur.w);
        __builtin_nontemporal_store(y, reinterpret_cast<v4f*>(out + off));
        prev = cur;
    }
}

extern "C" void kernel_launch(void* const* d_in, const int* in_sizes, int n_in,
                              void* d_out, int out_size, void* d_ws, size_t ws_size,
                              hipStream_t stream) {
    const float* u      = (const float*)d_in[0];
    const float* A_real = (const float*)d_in[1];
    const float* A_imag = (const float*)d_in[2];
    const float* B_real = (const float*)d_in[3];
    const float* B_imag = (const float*)d_in[4];
    const float* C_real = (const float*)d_in[5];
    const float* C_imag = (const float*)d_in[6];
    const float* Dp     = (const float*)d_in[7];
    float* out = (float*)d_out;

    float* c0 = (float*)d_ws;        // D_MODEL floats
    float* c1 = c0 + D_MODEL;        // D_MODEL floats  (16 KB total)

    s4d_coef_kernel<<<dim3(D_MODEL / 256), dim3(256), 0, stream>>>(
        A_real, A_imag, B_real, B_imag, C_real, C_imag, Dp, c0, c1);

    dim3 grid(D_MODEL / 1024, LSEQ / T_CHUNK, BATCH);
    s4d_conv_kernel<<<grid, dim3(256), 0, stream>>>(u, c0, c1, out);
}

// Round 3
// 440.523 us; speedup vs baseline: 1.0839x; 1.0417x over previous
//
#include <hip/hip_runtime.h>

// S4D (buggy-faithful reference): the whole FFT pipeline reduces to
//   y[b,t,d] = (k0[d] + D[d]) * u[b,t,d] + k1[d] * u[b,t-1,d]
// where [k0,k1] is the length-h (=2) "kernel" from the reference:
//   dA = [[z0,-1],[-1,z1]] (off-diag are -1 by the elementwise division),
//   P  = dA^L (L=256 -> 8 squarings), M = I - P,
//   k_n = Re( C_n * (M[n,0]*B0 + M[n,1]*B1) ).
// Entries of P reach ~2e19, so the setup math is done in fp64.

#define D_MODEL 2048
#define BATCH   128
#define LSEQ    256
#define HSTATE  2
#define T_CHUNK 32

// Native clang vector type: __builtin_nontemporal_store requires a scalar or
// native vector (HIP's float4 is a class and is rejected).
typedef float v4f __attribute__((ext_vector_type(4)));

struct cd { double re, im; };
__device__ __forceinline__ cd cmul(cd a, cd b) {
    return { a.re*b.re - a.im*b.im, a.re*b.im + a.im*b.re };
}
__device__ __forceinline__ cd cadd(cd a, cd b) { return { a.re + b.re, a.im + b.im }; }
__device__ __forceinline__ cd cdiv(cd a, cd b) {
    double inv = 1.0 / (b.re*b.re + b.im*b.im);
    return { (a.re*b.re + a.im*b.im) * inv, (a.im*b.re - a.re*b.im) * inv };
}

// One thread per channel d: compute c0[d] = k0[d] + D[d], c1[d] = k1[d].
__global__ __launch_bounds__(256) void s4d_coef_kernel(
        const float* __restrict__ A_real, const float* __restrict__ A_imag,
        const float* __restrict__ B_real, const float* __restrict__ B_imag,
        const float* __restrict__ C_real, const float* __restrict__ C_imag,
        const float* __restrict__ Dp,
        float* __restrict__ c0, float* __restrict__ c1) {
    int d = blockIdx.x * blockDim.x + threadIdx.x;
    if (d >= D_MODEL) return;

    // z_n = (1 + A_n/2) / (1 - A_n/2),  A_n = -exp(A_real) + i*A_imag
    cd z[HSTATE];
    #pragma unroll
    for (int n = 0; n < HSTATE; ++n) {
        double ar = -exp((double)A_real[d * HSTATE + n]);
        double ai = (double)A_imag[d * HSTATE + n];
        cd num = { 1.0 + 0.5 * ar,  0.5 * ai };
        cd den = { 1.0 - 0.5 * ar, -0.5 * ai };
        z[n] = cdiv(num, den);
    }

    // dA = [[z0, -1], [-1, z1]];  P = dA^256 via 8 squarings (fp64)
    cd m00 = z[0], m01 = { -1.0, 0.0 }, m10 = { -1.0, 0.0 }, m11 = z[1];
    #pragma unroll
    for (int s = 0; s < 8; ++s) {
        cd a = cadd(cmul(m00, m00), cmul(m01, m10));
        cd b = cadd(cmul(m00, m01), cmul(m01, m11));
        cd c = cadd(cmul(m10, m00), cmul(m11, m10));
        cd e = cadd(cmul(m10, m01), cmul(m11, m11));
        m00 = a; m01 = b; m10 = c; m11 = e;
    }

    // M = I - P
    cd M00 = { 1.0 - m00.re, -m00.im }, M01 = { -m01.re, -m01.im };
    cd M10 = { -m10.re, -m10.im },      M11 = { 1.0 - m11.re, -m11.im };

    cd B0 = { (double)B_real[d*2+0], (double)B_imag[d*2+0] };
    cd B1 = { (double)B_real[d*2+1], (double)B_imag[d*2+1] };
    cd C0 = { (double)C_real[d*2+0], (double)C_imag[d*2+0] };
    cd C1 = { (double)C_real[d*2+1], (double)C_imag[d*2+1] };

    cd k0 = cmul(C0, cadd(cmul(M00, B0), cmul(M01, B1)));
    cd k1 = cmul(C1, cadd(cmul(M10, B0), cmul(M11, B1)));

    c0[d] = (float)(k0.re + (double)Dp[d]);
    c1[d] = (float)k1.re;
}

// 2-tap causal conv along t, channels innermost (coalesced 16B loads).
// Block = 512 threads x 4 floats = 8 KB = exactly ONE full channel-row, so a
// block marching T_CHUNK=32 t-steps streams LINEARLY through a contiguous
// 256 KB region (like the 6.5 TB/s fill kernel) instead of 4 KB hops with
// an 8 KB stride — each DRAM page is touched exactly once, by one block.
// grid = (LSEQ/T_CHUNK, BATCH) = (8,128) = 1024 blocks = 4 blocks/CU x
// 8 waves = 32 waves/CU (occupancy cap). u[t-1] carried in register ->
// every u element loaded once (+1/32 boundary rows). unroll 8 keeps 8
// independent 1 KiB loads in flight per wave; non-temporal stores keep the
// write-once output out of L2/L3.
__global__ __launch_bounds__(512) void s4d_conv_kernel(
        const float* __restrict__ u,
        const float* __restrict__ c0, const float* __restrict__ c1,
        float* __restrict__ out) {
    const int d  = threadIdx.x * 4;          // 0..2047, full row per block
    const int b  = blockIdx.y;
    const int t0 = blockIdx.x * T_CHUNK;

    const v4f k0 = *reinterpret_cast<const v4f*>(c0 + d);
    const v4f k1 = *reinterpret_cast<const v4f*>(c1 + d);

    const size_t base = (size_t)b * LSEQ * D_MODEL + (size_t)d;

    v4f prev;
    if (t0 == 0) {
        prev = (v4f){0.f, 0.f, 0.f, 0.f};
    } else {
        prev = *reinterpret_cast<const v4f*>(u + base + (size_t)(t0 - 1) * D_MODEL);
    }

    #pragma unroll 8
    for (int t = t0; t < t0 + T_CHUNK; ++t) {
        const size_t off = base + (size_t)t * D_MODEL;
        v4f cur = *reinterpret_cast<const v4f*>(u + off);
        v4f y;
        y.x = fmaf(k1.x, prev.x, k0.x * cur.x);
        y.y = fmaf(k1.y, prev.y, k0.y * cur.y);
        y.z = fmaf(k1.z, prev.z, k0.z * cur.z);
        y.w = fmaf(k1.w, prev.w, k0.w * cur.w);
        __builtin_nontemporal_store(y, reinterpret_cast<v4f*>(out + off));
        prev = cur;
    }
}

extern "C" void kernel_launch(void* const* d_in, const int* in_sizes, int n_in,
                              void* d_out, int out_size, void* d_ws, size_t ws_size,
                              hipStream_t stream) {
    const float* u      = (const float*)d_in[0];
    const float* A_real = (const float*)d_in[1];
    const float* A_imag = (const float*)d_in[2];
    const float* B_real = (const float*)d_in[3];
    const float* B_imag = (const float*)d_in[4];
    const float* C_real = (const float*)d_in[5];
    const float* C_imag = (const float*)d_in[6];
    const float* Dp     = (const float*)d_in[7];
    float* out = (float*)d_out;

    float* c0 = (float*)d_ws;        // D_MODEL floats
    float* c1 = c0 + D_MODEL;        // D_MODEL floats  (16 KB total)

    s4d_coef_kernel<<<dim3(D_MODEL / 256), dim3(256), 0, stream>>>(
        A_real, A_imag, B_real, B_imag, C_real, C_imag, Dp, c0, c1);

    dim3 grid(LSEQ / T_CHUNK, BATCH);
    s4d_conv_kernel<<<grid, dim3(512), 0, stream>>>(u, c0, c1, out);
}